// Round 1
// baseline (1087.223 us; speedup 1.0000x reference)
//
#include <hip/hip_runtime.h>

// Problem constants (from reference): N=65536, E=1048576, nfeat=64, nhid=128.
// All inputs fp32; edge_index int32 (harness: integer -> const int*).

#define BN_EPS 1e-5f

// ---------------- K0: h = x (copy into workspace) ----------------
__global__ __launch_bounds__(256) void k0_copy(const float4* __restrict__ x,
                                               float4* __restrict__ h, int n4) {
    int i = blockIdx.x * 256 + threadIdx.x;
    if (i < n4) h[i] = x[i];
}

// ---------------- K1: edge scatter: h[dst] += x[src] ----------------
// One wave per edge: lane = feature (64 feats). Coalesced 256B gather,
// contiguous 256B atomic-add region per edge.
__global__ __launch_bounds__(256) void k1_scatter(const int* __restrict__ ei,
                                                  const float* __restrict__ x,
                                                  float* __restrict__ h, int E) {
    int tid = blockIdx.x * 256 + threadIdx.x;
    int e = tid >> 6;
    int f = tid & 63;
    if (e < E) {
        int src = ei[e];
        int dst = ei[E + e];
        atomicAdd(&h[dst * 64 + f], x[src * 64 + f]);
    }
}

// ---------------- K2: spectral-norm sigmas (1 block, 128 thr) ----------------
// sigma = ||W v||^2 / (||W v|| + 1e-12), v = (W^T u)/(||W^T u|| + 1e-12)
__global__ __launch_bounds__(128) void k2_sigma(const float* __restrict__ W1,
                                                const float* __restrict__ u1,
                                                const float* __restrict__ W2,
                                                const float* __restrict__ u2,
                                                float* __restrict__ sinv) {
    __shared__ float v[128];
    __shared__ float red[128];
    int t = threadIdx.x;

    // --- W1 (128x64) ---
    float vj = 0.f;
    if (t < 64) {
        for (int i = 0; i < 128; i++) vj += W1[i * 64 + t] * u1[i];
    }
    red[t] = (t < 64) ? vj * vj : 0.f;
    __syncthreads();
    for (int s = 64; s > 0; s >>= 1) { if (t < s) red[t] += red[t + s]; __syncthreads(); }
    float nv = sqrtf(red[0]);
    __syncthreads();
    if (t < 64) v[t] = vj / (nv + 1e-12f);
    __syncthreads();
    float ti = 0.f;
    for (int j = 0; j < 64; j++) ti += W1[t * 64 + j] * v[j];
    red[t] = ti * ti;
    __syncthreads();
    for (int s = 64; s > 0; s >>= 1) { if (t < s) red[t] += red[t + s]; __syncthreads(); }
    if (t == 0) {
        float nt2 = red[0];
        float nt = sqrtf(nt2);
        float sigma = nt2 / (nt + 1e-12f);
        sinv[0] = 1.f / sigma;
    }
    __syncthreads();

    // --- W2 (128x128) ---
    float v2 = 0.f;
    for (int i = 0; i < 128; i++) v2 += W2[i * 128 + t] * u2[i];
    red[t] = v2 * v2;
    __syncthreads();
    for (int s = 64; s > 0; s >>= 1) { if (t < s) red[t] += red[t + s]; __syncthreads(); }
    nv = sqrtf(red[0]);
    __syncthreads();
    v[t] = v2 / (nv + 1e-12f);
    __syncthreads();
    ti = 0.f;
    for (int j = 0; j < 128; j++) ti += W2[t * 128 + j] * v[j];
    red[t] = ti * ti;
    __syncthreads();
    for (int s = 64; s > 0; s >>= 1) { if (t < s) red[t] += red[t + s]; __syncthreads(); }
    if (t == 0) {
        float nt2 = red[0];
        float nt = sqrtf(nt2);
        float sigma = nt2 / (nt + 1e-12f);
        sinv[1] = 1.f / sigma;
    }
}

// ---------------- K3: h1 = relu(s1*(h @ W1^T) + b1), + BN partial sums -------
// 64-node tile per block (256 threads). h1 written to d_out (scratch use).
// partial[block*256 + f]      = sum over tile nodes of h1[:,f]
// partial[block*256 + 128 + f]= sum over tile nodes of h1[:,f]^2
__global__ __launch_bounds__(256) void k3_gemm1(const float* __restrict__ h,
                                                const float* __restrict__ W1,
                                                const float* __restrict__ b1,
                                                const float* __restrict__ sinv,
                                                float* __restrict__ h1out,
                                                float* __restrict__ partial) {
    __shared__ float htile[64 * 68];   // 64 nodes x 64 feats, row stride 68
    __shared__ float h1t[64 * 132];    // 64 nodes x 128 hid, row stride 132
    __shared__ float bred[8 * 128];
    int t = threadIdx.x;
    int n0 = blockIdx.x * 64;

    // Load tile (coalesced float4)
    {
        const float4* src = (const float4*)(h + (size_t)n0 * 64);
#pragma unroll
        for (int i = 0; i < 4; i++) {
            int idx4 = i * 256 + t;        // 0..1023
            int node = idx4 >> 4;          // 16 float4 per node row
            int f4 = idx4 & 15;
            *((float4*)&htile[node * 68 + f4 * 4]) = src[idx4];
        }
    }
    __syncthreads();

    int nl = t >> 2, q = t & 3;
    float4 hr[16];
#pragma unroll
    for (int k4 = 0; k4 < 16; k4++)
        hr[k4] = *((const float4*)&htile[nl * 68 + k4 * 4]);

    float s1 = sinv[0];
#pragma unroll
    for (int ji = 0; ji < 32; ji++) {
        int j = q + 4 * ji;
        const float4* w = (const float4*)(W1 + j * 64);
        float acc = 0.f;
#pragma unroll
        for (int k4 = 0; k4 < 16; k4++) {
            float4 wv = w[k4];
            acc += hr[k4].x * wv.x + hr[k4].y * wv.y + hr[k4].z * wv.z + hr[k4].w * wv.w;
        }
        float val = fmaxf(fmaf(acc, s1, b1[j]), 0.f);
        h1t[nl * 132 + j] = val;
    }
    __syncthreads();

    // Coalesced writeout + per-thread BN accumulation (4 fixed features each)
    float4 bs = {0.f, 0.f, 0.f, 0.f}, bq = {0.f, 0.f, 0.f, 0.f};
    {
        float4* dst = (float4*)(h1out + (size_t)n0 * 128);
#pragma unroll
        for (int i = 0; i < 8; i++) {
            int idx4 = i * 256 + t;        // 0..2047
            int node = idx4 >> 5;          // 32 float4 per node row
            int f4 = idx4 & 31;
            float4 v = *((const float4*)&h1t[node * 132 + f4 * 4]);
            dst[idx4] = v;
            bs.x += v.x; bs.y += v.y; bs.z += v.z; bs.w += v.w;
            bq.x += v.x * v.x; bq.y += v.y * v.y; bq.z += v.z * v.z; bq.w += v.w * v.w;
        }
    }
    int m = t >> 5;                 // 8 groups
    int fb = (t & 31) * 4;          // feature base (constant per thread)
    __syncthreads();
    bred[m * 128 + fb + 0] = bs.x; bred[m * 128 + fb + 1] = bs.y;
    bred[m * 128 + fb + 2] = bs.z; bred[m * 128 + fb + 3] = bs.w;
    __syncthreads();
    if (t < 128) {
        float s = 0.f;
#pragma unroll
        for (int g = 0; g < 8; g++) s += bred[g * 128 + t];
        partial[blockIdx.x * 256 + t] = s;
    }
    __syncthreads();
    bred[m * 128 + fb + 0] = bq.x; bred[m * 128 + fb + 1] = bq.y;
    bred[m * 128 + fb + 2] = bq.z; bred[m * 128 + fb + 3] = bq.w;
    __syncthreads();
    if (t < 128) {
        float s = 0.f;
#pragma unroll
        for (int g = 0; g < 8; g++) s += bred[g * 128 + t];
        partial[blockIdx.x * 256 + 128 + t] = s;
    }
}

// ---------------- K4: fold BN + sigma2 into W2f, b2f (1 block) ----------------
__global__ __launch_bounds__(256) void k4_fold(const float* __restrict__ partial,
                                               int nblk, int N,
                                               const float* __restrict__ gamma,
                                               const float* __restrict__ beta,
                                               const float* __restrict__ W2,
                                               const float* __restrict__ b2,
                                               const float* __restrict__ sinv,
                                               float* __restrict__ W2f,
                                               float* __restrict__ b2f) {
    __shared__ float sums[256];
    __shared__ float a_s[128], c_s[128];
    int t = threadIdx.x;
    float t0 = 0.f, t1 = 0.f, t2 = 0.f, t3 = 0.f;
    for (int b = 0; b < nblk; b += 4) {
        t0 += partial[(b + 0) * 256 + t];
        t1 += partial[(b + 1) * 256 + t];
        t2 += partial[(b + 2) * 256 + t];
        t3 += partial[(b + 3) * 256 + t];
    }
    sums[t] = (t0 + t1) + (t2 + t3);
    __syncthreads();
    if (t < 128) {
        float mean = sums[t] / (float)N;
        float var = sums[t + 128] / (float)N - mean * mean;
        float rstd = rsqrtf(var + BN_EPS);
        float a = rstd * gamma[t];
        a_s[t] = a;
        c_s[t] = beta[t] - mean * a;
    }
    __syncthreads();
    if (t < 128) {
        float s2 = sinv[1];
        float accb = 0.f;
        for (int j = 0; j < 128; j++) {
            float w = W2[t * 128 + j] * s2;
            W2f[t * 128 + j] = w * a_s[j];
            accb += w * c_s[j];
        }
        b2f[t] = b2[t] + accb;
    }
}

// ---------------- K5: out = h1 @ W2f^T + b2f, in place on d_out ----------------
__global__ __launch_bounds__(256) void k5_gemm2(const float* __restrict__ W2f,
                                                const float* __restrict__ b2f,
                                                float* __restrict__ io) {
    __shared__ float ht[64 * 132];
    int t = threadIdx.x;
    int n0 = blockIdx.x * 64;
    float4* g = (float4*)(io + (size_t)n0 * 128);
#pragma unroll
    for (int i = 0; i < 8; i++) {
        int idx4 = i * 256 + t;
        int node = idx4 >> 5, f4 = idx4 & 31;
        *((float4*)&ht[node * 132 + f4 * 4]) = g[idx4];
    }
    __syncthreads();

    int nl = t >> 2, q = t & 3;
    float acc[32];
#pragma unroll
    for (int oi = 0; oi < 32; oi++) acc[oi] = 0.f;

#pragma unroll
    for (int half = 0; half < 2; half++) {
        float4 hr[16];
#pragma unroll
        for (int k4 = 0; k4 < 16; k4++)
            hr[k4] = *((const float4*)&ht[nl * 132 + half * 64 + k4 * 4]);
#pragma unroll
        for (int oi = 0; oi < 32; oi++) {
            int o = q + 4 * oi;
            const float4* w = (const float4*)(W2f + o * 128 + half * 64);
            float a = 0.f;
#pragma unroll
            for (int k4 = 0; k4 < 16; k4++) {
                float4 wv = w[k4];
                a += hr[k4].x * wv.x + hr[k4].y * wv.y + hr[k4].z * wv.z + hr[k4].w * wv.w;
            }
            acc[oi] += a;
        }
    }
    __syncthreads();  // all LDS reads complete before overwrite
#pragma unroll
    for (int oi = 0; oi < 32; oi++) {
        int o = q + 4 * oi;
        ht[nl * 132 + o] = acc[oi] + b2f[o];
    }
    __syncthreads();
#pragma unroll
    for (int i = 0; i < 8; i++) {
        int idx4 = i * 256 + t;
        int node = idx4 >> 5, f4 = idx4 & 31;
        g[idx4] = *((const float4*)&ht[node * 132 + f4 * 4]);
    }
}

extern "C" void kernel_launch(void* const* d_in, const int* in_sizes, int n_in,
                              void* d_out, int out_size, void* d_ws, size_t ws_size,
                              hipStream_t stream) {
    const float* x     = (const float*)d_in[0];
    const int*   ei    = (const int*)d_in[1];
    const float* W1    = (const float*)d_in[2];
    const float* b1    = (const float*)d_in[3];
    const float* u1    = (const float*)d_in[4];
    const float* gamma = (const float*)d_in[5];
    const float* beta  = (const float*)d_in[6];
    const float* W2    = (const float*)d_in[7];
    const float* b2    = (const float*)d_in[8];
    const float* u2    = (const float*)d_in[9];
    float* out = (float*)d_out;

    int N = in_sizes[0] / 64;     // 65536
    int E = in_sizes[1] / 2;      // 1048576
    int nblk = N / 64;            // 1024

    char* ws = (char*)d_ws;
    float* h       = (float*)ws;                                   // N*64 floats
    float* partial = (float*)(ws + (size_t)N * 64 * 4);            // nblk*256 floats
    float* sinv    = (float*)(ws + (size_t)N * 64 * 4 + (size_t)nblk * 256 * 4);
    float* W2f     = sinv + 16;                                    // 128*128 floats
    float* b2f     = W2f + 128 * 128;                              // 128 floats

    // h = x
    int n4 = N * 16;
    k0_copy<<<(n4 + 255) / 256, 256, 0, stream>>>((const float4*)x, (float4*)h, n4);
    // sigmas (independent of scatter)
    k2_sigma<<<1, 128, 0, stream>>>(W1, u1, W2, u2, sinv);
    // h += scatter(x[src] -> dst)
    int ethreads = E * 64;
    k1_scatter<<<(ethreads + 255) / 256, 256, 0, stream>>>(ei, x, h, E);
    // h1 = relu(gemm1) -> d_out, BN partials
    k3_gemm1<<<nblk, 256, 0, stream>>>(h, W1, b1, sinv, out, partial);
    // fold BN + sigma2
    k4_fold<<<1, 256, 0, stream>>>(partial, nblk, N, gamma, beta, W2, b2, sinv, W2f, b2f);
    // out = h1 @ W2f^T + b2f (in place)
    k5_gemm2<<<nblk, 256, 0, stream>>>(W2f, b2f, out);
}

// Round 2
// 534.926 us; speedup vs baseline: 2.0325x; 2.0325x over previous
//
#include <hip/hip_runtime.h>

// N=65536, E=1048576, nfeat=64, nhid=128. All fp32; edge_index int32.

#define BN_EPS 1e-5f

// ---------------- K0: h = x (copy into workspace) ----------------
__global__ __launch_bounds__(256) void k0_copy(const float4* __restrict__ x,
                                               float4* __restrict__ h, int n4) {
    int i = blockIdx.x * 256 + threadIdx.x;
    if (i < n4) h[i] = x[i];
}

// ---------------- K1: edge scatter: h[dst] += x[src] ----------------
__global__ __launch_bounds__(256) void k1_scatter(const int* __restrict__ ei,
                                                  const float* __restrict__ x,
                                                  float* __restrict__ h, int E) {
    int tid = blockIdx.x * 256 + threadIdx.x;
    int e = tid >> 6;
    int f = tid & 63;
    if (e < E) {
        int src = ei[e];
        int dst = ei[E + e];
        atomicAdd(&h[dst * 64 + f], x[src * 64 + f]);
    }
}

// ---------------- K2: spectral-norm sigmas (1 block, 128 thr) ----------------
__global__ __launch_bounds__(128) void k2_sigma(const float* __restrict__ W1,
                                                const float* __restrict__ u1,
                                                const float* __restrict__ W2,
                                                const float* __restrict__ u2,
                                                float* __restrict__ sinv) {
    __shared__ float v[128];
    __shared__ float red[128];
    int t = threadIdx.x;

    float vj = 0.f;
    if (t < 64) {
        for (int i = 0; i < 128; i++) vj += W1[i * 64 + t] * u1[i];
    }
    red[t] = (t < 64) ? vj * vj : 0.f;
    __syncthreads();
    for (int s = 64; s > 0; s >>= 1) { if (t < s) red[t] += red[t + s]; __syncthreads(); }
    float nv = sqrtf(red[0]);
    __syncthreads();
    if (t < 64) v[t] = vj / (nv + 1e-12f);
    __syncthreads();
    float ti = 0.f;
    for (int j = 0; j < 64; j++) ti += W1[t * 64 + j] * v[j];
    red[t] = ti * ti;
    __syncthreads();
    for (int s = 64; s > 0; s >>= 1) { if (t < s) red[t] += red[t + s]; __syncthreads(); }
    if (t == 0) {
        float nt2 = red[0];
        float nt = sqrtf(nt2);
        sinv[0] = (nt + 1e-12f) / nt2;
    }
    __syncthreads();

    float v2 = 0.f;
    for (int i = 0; i < 128; i++) v2 += W2[i * 128 + t] * u2[i];
    red[t] = v2 * v2;
    __syncthreads();
    for (int s = 64; s > 0; s >>= 1) { if (t < s) red[t] += red[t + s]; __syncthreads(); }
    nv = sqrtf(red[0]);
    __syncthreads();
    v[t] = v2 / (nv + 1e-12f);
    __syncthreads();
    ti = 0.f;
    for (int j = 0; j < 128; j++) ti += W2[t * 128 + j] * v[j];
    red[t] = ti * ti;
    __syncthreads();
    for (int s = 64; s > 0; s >>= 1) { if (t < s) red[t] += red[t + s]; __syncthreads(); }
    if (t == 0) {
        float nt2 = red[0];
        float nt = sqrtf(nt2);
        sinv[1] = (nt + 1e-12f) / nt2;
    }
}

// ---------------- K3: h1 = relu(s1*(h @ W1^T) + b1) + BN partials ----------------
// 128-node tile, 256 threads, 8x8 register tile. h and W1 both staged in LDS
// with rotate-chunk swizzle -> all ds_read_b128 fragments <=2-way bank alias.
__global__ __launch_bounds__(256) void k3_gemm1(const float* __restrict__ h,
                                                const float* __restrict__ W1,
                                                const float* __restrict__ b1,
                                                const float* __restrict__ sinv,
                                                float* __restrict__ h1out,
                                                float* __restrict__ partial) {
    __shared__ float htile[128 * 64];   // 32 KB, swizzled chunks (16 per row)
    __shared__ float w1s[128 * 64];     // 32 KB, swizzled chunks
    int t = threadIdx.x;
    int n0 = blockIdx.x * 128;

    // stage h tile (128 nodes x 64 feats) and W1 (128 x 64), coalesced
    {
        const float4* src = (const float4*)(h + (size_t)n0 * 64);
        const float4* wsrc = (const float4*)W1;
#pragma unroll
        for (int i = 0; i < 8; i++) {
            int idx = i * 256 + t;          // 0..2047
            int row = idx >> 4;
            int c = idx & 15;
            int cs = (c + (row >> 3)) & 15; // rotate swizzle
            *((float4*)&htile[row * 64 + cs * 4]) = src[idx];
        }
#pragma unroll
        for (int i = 0; i < 8; i++) {
            int idx = i * 256 + t;
            int row = idx >> 4;
            int c = idx & 15;
            int cs = (c + (row >> 3)) & 15;
            *((float4*)&w1s[row * 64 + cs * 4]) = wsrc[idx];
        }
    }
    __syncthreads();

    int ty = t >> 4;        // node group (8 nodes each)
    int tx = t & 15;        // output group (8 outputs each)

    float acc[8][8];
#pragma unroll
    for (int i = 0; i < 8; i++)
#pragma unroll
        for (int j = 0; j < 8; j++) acc[i][j] = 0.f;

#pragma unroll
    for (int c = 0; c < 16; c++) {
        int ca = (c + ty) & 15;   // node = ty*8+i -> row>>3 == ty
        int cb = (c + tx) & 15;   // o    = tx*8+j -> row>>3 == tx
        float4 a[8], b[8];
#pragma unroll
        for (int i = 0; i < 8; i++)
            a[i] = *((const float4*)&htile[(ty * 8 + i) * 64 + ca * 4]);
#pragma unroll
        for (int j = 0; j < 8; j++)
            b[j] = *((const float4*)&w1s[(tx * 8 + j) * 64 + cb * 4]);
#pragma unroll
        for (int i = 0; i < 8; i++)
#pragma unroll
            for (int j = 0; j < 8; j++)
                acc[i][j] += a[i].x * b[j].x + a[i].y * b[j].y +
                             a[i].z * b[j].z + a[i].w * b[j].w;
    }

    // epilogue: relu(acc*s1 + b1), write out, BN partial sums
    float s1 = sinv[0];
    float4 b1lo = *((const float4*)&b1[tx * 8]);
    float4 b1hi = *((const float4*)&b1[tx * 8 + 4]);
    float bb[8] = {b1lo.x, b1lo.y, b1lo.z, b1lo.w, b1hi.x, b1hi.y, b1hi.z, b1hi.w};

#pragma unroll
    for (int i = 0; i < 8; i++) {
#pragma unroll
        for (int j = 0; j < 8; j++)
            acc[i][j] = fmaxf(fmaf(acc[i][j], s1, bb[j]), 0.f);
        float4 v0 = {acc[i][0], acc[i][1], acc[i][2], acc[i][3]};
        float4 v1 = {acc[i][4], acc[i][5], acc[i][6], acc[i][7]};
        float* dst = h1out + (size_t)(n0 + ty * 8 + i) * 128 + tx * 8;
        *((float4*)dst) = v0;
        *((float4*)(dst + 4)) = v1;
    }

    // BN partials: reuse htile as reduction scratch (16 x 128, stride 132)
    float* red = htile;
    float ps[8], qs[8];
#pragma unroll
    for (int j = 0; j < 8; j++) {
        float s = 0.f, q = 0.f;
#pragma unroll
        for (int i = 0; i < 8; i++) { s += acc[i][j]; q += acc[i][j] * acc[i][j]; }
        ps[j] = s; qs[j] = q;
    }
    __syncthreads();
#pragma unroll
    for (int j = 0; j < 8; j++) red[ty * 132 + tx * 8 + j] = ps[j];
    __syncthreads();
    if (t < 128) {
        float s = 0.f;
#pragma unroll
        for (int g = 0; g < 16; g++) s += red[g * 132 + t];
        partial[blockIdx.x * 256 + t] = s;
    }
    __syncthreads();
#pragma unroll
    for (int j = 0; j < 8; j++) red[ty * 132 + tx * 8 + j] = qs[j];
    __syncthreads();
    if (t < 128) {
        float s = 0.f;
#pragma unroll
        for (int g = 0; g < 16; g++) s += red[g * 132 + t];
        partial[blockIdx.x * 256 + 128 + t] = s;
    }
}

// ---------------- K4: fold BN + sigma2 into W2f, b2f (1 block) ----------------
__global__ __launch_bounds__(256) void k4_fold(const float* __restrict__ partial,
                                               int nblk, int N,
                                               const float* __restrict__ gamma,
                                               const float* __restrict__ beta,
                                               const float* __restrict__ W2,
                                               const float* __restrict__ b2,
                                               const float* __restrict__ sinv,
                                               float* __restrict__ W2f,
                                               float* __restrict__ b2f) {
    __shared__ float sums[256];
    __shared__ float a_s[128], c_s[128];
    int t = threadIdx.x;
    float t0 = 0.f, t1 = 0.f, t2 = 0.f, t3 = 0.f;
    for (int b = 0; b < nblk; b += 4) {
        t0 += partial[(b + 0) * 256 + t];
        t1 += partial[(b + 1) * 256 + t];
        t2 += partial[(b + 2) * 256 + t];
        t3 += partial[(b + 3) * 256 + t];
    }
    sums[t] = (t0 + t1) + (t2 + t3);
    __syncthreads();
    if (t < 128) {
        float mean = sums[t] / (float)N;
        float var = sums[t + 128] / (float)N - mean * mean;
        float rstd = rsqrtf(var + BN_EPS);
        float a = rstd * gamma[t];
        a_s[t] = a;
        c_s[t] = beta[t] - mean * a;
    }
    __syncthreads();
    if (t < 128) {
        float s2 = sinv[1];
        float accb = 0.f;
        for (int j = 0; j < 128; j++) {
            float w = W2[t * 128 + j] * s2;
            W2f[t * 128 + j] = w * a_s[j];
            accb += w * c_s[j];
        }
        b2f[t] = b2[t] + accb;
    }
}

// ---------------- K5: out = h1 @ W2f^T + b2f, in place on d_out ----------------
// 64-node tile, 256 threads, K=128. W2f processed in two 64-output halves
// (32 KB each) so LDS = 64 KB. 4x4 register tile per half.
__global__ __launch_bounds__(256) void k5_gemm2(const float* __restrict__ W2f,
                                                const float* __restrict__ b2f,
                                                float* __restrict__ io) {
    __shared__ float htile[64 * 128];  // 32 KB, swizzled (32 chunks per row)
    __shared__ float w2s[64 * 128];    // 32 KB, one output-half of W2f
    int t = threadIdx.x;
    int n0 = blockIdx.x * 64;
    int ty = t >> 4;        // node group (4 nodes)
    int tx = t & 15;        // output group (4 outputs)

    // stage h1 tile: 64 nodes x 128 = 2048 float4
    {
        const float4* src = (const float4*)(io + (size_t)n0 * 128);
#pragma unroll
        for (int i = 0; i < 8; i++) {
            int idx = i * 256 + t;
            int row = idx >> 5;
            int c = idx & 31;
            int cs = (c + (row >> 2)) & 31;
            *((float4*)&htile[row * 128 + cs * 4]) = src[idx];
        }
    }

    float acc[2][4][4];
#pragma unroll
    for (int hh = 0; hh < 2; hh++)
#pragma unroll
        for (int i = 0; i < 4; i++)
#pragma unroll
            for (int j = 0; j < 4; j++) acc[hh][i][j] = 0.f;

    for (int half = 0; half < 2; half++) {
        __syncthreads();   // htile writes done / previous w2s reads done
        const float4* wsrc = (const float4*)(W2f + (size_t)half * 64 * 128);
#pragma unroll
        for (int i = 0; i < 8; i++) {
            int idx = i * 256 + t;
            int row = idx >> 5;
            int c = idx & 31;
            int cs = (c + (row >> 2)) & 31;
            *((float4*)&w2s[row * 128 + cs * 4]) = wsrc[idx];
        }
        __syncthreads();

#pragma unroll
        for (int c = 0; c < 32; c++) {
            int ca = (c + ty) & 31;   // node = ty*4+i -> row>>2 == ty
            int cb = (c + tx) & 31;   // o    = tx*4+j -> row>>2 == tx
            float4 a[4], b[4];
#pragma unroll
            for (int i = 0; i < 4; i++)
                a[i] = *((const float4*)&htile[(ty * 4 + i) * 128 + ca * 4]);
#pragma unroll
            for (int j = 0; j < 4; j++)
                b[j] = *((const float4*)&w2s[(tx * 4 + j) * 128 + cb * 4]);
#pragma unroll
            for (int i = 0; i < 4; i++)
#pragma unroll
                for (int j = 0; j < 4; j++)
                    acc[half][i][j] += a[i].x * b[j].x + a[i].y * b[j].y +
                                       a[i].z * b[j].z + a[i].w * b[j].w;
        }
    }

    // epilogue: add b2f, write back in place (only this block touches rows)
    float4 bf0 = *((const float4*)&b2f[tx * 4]);
    float4 bf1 = *((const float4*)&b2f[64 + tx * 4]);
#pragma unroll
    for (int i = 0; i < 4; i++) {
        float* dst = io + (size_t)(n0 + ty * 4 + i) * 128;
        float4 v0 = {acc[0][i][0] + bf0.x, acc[0][i][1] + bf0.y,
                     acc[0][i][2] + bf0.z, acc[0][i][3] + bf0.w};
        float4 v1 = {acc[1][i][0] + bf1.x, acc[1][i][1] + bf1.y,
                     acc[1][i][2] + bf1.z, acc[1][i][3] + bf1.w};
        *((float4*)(dst + tx * 4)) = v0;
        *((float4*)(dst + 64 + tx * 4)) = v1;
    }
}

extern "C" void kernel_launch(void* const* d_in, const int* in_sizes, int n_in,
                              void* d_out, int out_size, void* d_ws, size_t ws_size,
                              hipStream_t stream) {
    const float* x     = (const float*)d_in[0];
    const int*   ei    = (const int*)d_in[1];
    const float* W1    = (const float*)d_in[2];
    const float* b1    = (const float*)d_in[3];
    const float* u1    = (const float*)d_in[4];
    const float* gamma = (const float*)d_in[5];
    const float* beta  = (const float*)d_in[6];
    const float* W2    = (const float*)d_in[7];
    const float* b2    = (const float*)d_in[8];
    const float* u2    = (const float*)d_in[9];
    float* out = (float*)d_out;

    int N = in_sizes[0] / 64;     // 65536
    int E = in_sizes[1] / 2;      // 1048576
    int nblk1 = N / 128;          // 512 (k3 tiles)
    int nblk2 = N / 64;           // 1024 (k5 tiles)

    char* ws = (char*)d_ws;
    float* h       = (float*)ws;                                    // N*64
    float* partial = (float*)(ws + (size_t)N * 64 * 4);             // nblk1*256
    float* sinv    = (float*)(ws + (size_t)N * 64 * 4 + (size_t)nblk1 * 256 * 4);
    float* W2f     = sinv + 16;                                     // 128*128
    float* b2f     = W2f + 128 * 128;                               // 128

    int n4 = N * 16;
    k0_copy<<<(n4 + 255) / 256, 256, 0, stream>>>((const float4*)x, (float4*)h, n4);
    k2_sigma<<<1, 128, 0, stream>>>(W1, u1, W2, u2, sinv);
    int ethreads = E * 64;
    k1_scatter<<<(ethreads + 255) / 256, 256, 0, stream>>>(ei, x, h, E);
    k3_gemm1<<<nblk1, 256, 0, stream>>>(h, W1, b1, sinv, out, partial);
    k4_fold<<<1, 256, 0, stream>>>(partial, nblk1, N, gamma, beta, W2, b2, sinv, W2f, b2f);
    k5_gemm2<<<nblk2, 256, 0, stream>>>(W2f, b2f, out);
}

// Round 3
// 502.167 us; speedup vs baseline: 2.1651x; 1.0652x over previous
//
#include <hip/hip_runtime.h>

// N=65536, E=1048576, nfeat=64, nhid=128. All fp32; edge_index int32.

#define BN_EPS 1e-5f

// ---------------- CSR build: zero / count / scan / fill ----------------
__global__ __launch_bounds__(256) void kzero(int* __restrict__ deg, int N) {
    int i = blockIdx.x * 256 + threadIdx.x;
    if (i < N) deg[i] = 0;
}

__global__ __launch_bounds__(256) void kcount(const int* __restrict__ ei,
                                              int* __restrict__ deg, int E) {
    int e = blockIdx.x * 256 + threadIdx.x;
    if (e < E) atomicAdd(&deg[ei[E + e]], 1);
}

// single block, 1024 threads, chunk = 64 -> N = 65536
__global__ __launch_bounds__(1024) void kscan(const int* __restrict__ deg,
                                              int* __restrict__ offset,
                                              int* __restrict__ cursor, int N) {
    __shared__ int part[1024];
    int t = threadIdx.x;
    int base = t * 64;
    int sum = 0;
#pragma unroll 8
    for (int i = 0; i < 64; i++) sum += deg[base + i];
    part[t] = sum;
    __syncthreads();
    // Hillis-Steele inclusive scan
    for (int off = 1; off < 1024; off <<= 1) {
        int v = (t >= off) ? part[t - off] : 0;
        __syncthreads();
        part[t] += v;
        __syncthreads();
    }
    int run = part[t] - sum;   // exclusive base for this chunk
#pragma unroll 8
    for (int i = 0; i < 64; i++) {
        int d = deg[base + i];
        offset[base + i] = run;
        cursor[base + i] = run;
        run += d;
    }
    if (t == 1023) offset[N] = run;
}

__global__ __launch_bounds__(256) void kfill(const int* __restrict__ ei,
                                             int* __restrict__ cursor,
                                             int* __restrict__ csr, int E) {
    int e = blockIdx.x * 256 + threadIdx.x;
    if (e < E) {
        int src = ei[e];
        int dst = ei[E + e];
        int pos = atomicAdd(&cursor[dst], 1);
        csr[pos] = src;
    }
}

// ---------------- kagg: h[n] = x[n] + sum_{src in csr[n]} x[src] ----------------
// One wave per node; lane = feature. csr reads are wave-uniform (SMEM path);
// x-row gathers are 256B coalesced; 4-edge unroll for ILP.
__global__ __launch_bounds__(256) void kagg(const int* __restrict__ offset,
                                            const int* __restrict__ csr,
                                            const float* __restrict__ x,
                                            float* __restrict__ h, int N) {
    int w = (blockIdx.x * 256 + threadIdx.x) >> 6;
    int lane = threadIdx.x & 63;
    if (w >= N) return;
    int beg = offset[w];
    int end = offset[w + 1];
    float a0 = x[(size_t)w * 64 + lane];
    float a1 = 0.f, a2 = 0.f, a3 = 0.f;
    int j = beg;
    for (; j + 4 <= end; j += 4) {
        int s0 = csr[j + 0];
        int s1 = csr[j + 1];
        int s2 = csr[j + 2];
        int s3 = csr[j + 3];
        a0 += x[(size_t)s0 * 64 + lane];
        a1 += x[(size_t)s1 * 64 + lane];
        a2 += x[(size_t)s2 * 64 + lane];
        a3 += x[(size_t)s3 * 64 + lane];
    }
    for (; j < end; j++) a0 += x[(size_t)csr[j] * 64 + lane];
    h[(size_t)w * 64 + lane] = (a0 + a1) + (a2 + a3);
}

// ---------------- K2: spectral-norm sigmas (1 block, 128 thr) ----------------
__global__ __launch_bounds__(128) void k2_sigma(const float* __restrict__ W1,
                                                const float* __restrict__ u1,
                                                const float* __restrict__ W2,
                                                const float* __restrict__ u2,
                                                float* __restrict__ sinv) {
    __shared__ float v[128];
    __shared__ float red[128];
    int t = threadIdx.x;

    float vj = 0.f;
    if (t < 64) {
        for (int i = 0; i < 128; i++) vj += W1[i * 64 + t] * u1[i];
    }
    red[t] = (t < 64) ? vj * vj : 0.f;
    __syncthreads();
    for (int s = 64; s > 0; s >>= 1) { if (t < s) red[t] += red[t + s]; __syncthreads(); }
    float nv = sqrtf(red[0]);
    __syncthreads();
    if (t < 64) v[t] = vj / (nv + 1e-12f);
    __syncthreads();
    float ti = 0.f;
    for (int j = 0; j < 64; j++) ti += W1[t * 64 + j] * v[j];
    red[t] = ti * ti;
    __syncthreads();
    for (int s = 64; s > 0; s >>= 1) { if (t < s) red[t] += red[t + s]; __syncthreads(); }
    if (t == 0) {
        float nt2 = red[0];
        float nt = sqrtf(nt2);
        sinv[0] = (nt + 1e-12f) / nt2;
    }
    __syncthreads();

    float v2 = 0.f;
    for (int i = 0; i < 128; i++) v2 += W2[i * 128 + t] * u2[i];
    red[t] = v2 * v2;
    __syncthreads();
    for (int s = 64; s > 0; s >>= 1) { if (t < s) red[t] += red[t + s]; __syncthreads(); }
    nv = sqrtf(red[0]);
    __syncthreads();
    v[t] = v2 / (nv + 1e-12f);
    __syncthreads();
    ti = 0.f;
    for (int j = 0; j < 128; j++) ti += W2[t * 128 + j] * v[j];
    red[t] = ti * ti;
    __syncthreads();
    for (int s = 64; s > 0; s >>= 1) { if (t < s) red[t] += red[t + s]; __syncthreads(); }
    if (t == 0) {
        float nt2 = red[0];
        float nt = sqrtf(nt2);
        sinv[1] = (nt + 1e-12f) / nt2;
    }
}

// ---------------- K3: h1 = relu(s1*(h @ W1^T) + b1) + BN partials ----------------
__global__ __launch_bounds__(256) void k3_gemm1(const float* __restrict__ h,
                                                const float* __restrict__ W1,
                                                const float* __restrict__ b1,
                                                const float* __restrict__ sinv,
                                                float* __restrict__ h1out,
                                                float* __restrict__ partial) {
    __shared__ float htile[128 * 64];   // 32 KB, swizzled chunks (16 per row)
    __shared__ float w1s[128 * 64];     // 32 KB, swizzled chunks
    int t = threadIdx.x;
    int n0 = blockIdx.x * 128;

    {
        const float4* src = (const float4*)(h + (size_t)n0 * 64);
        const float4* wsrc = (const float4*)W1;
#pragma unroll
        for (int i = 0; i < 8; i++) {
            int idx = i * 256 + t;
            int row = idx >> 4;
            int c = idx & 15;
            int cs = (c + (row >> 3)) & 15;
            *((float4*)&htile[row * 64 + cs * 4]) = src[idx];
        }
#pragma unroll
        for (int i = 0; i < 8; i++) {
            int idx = i * 256 + t;
            int row = idx >> 4;
            int c = idx & 15;
            int cs = (c + (row >> 3)) & 15;
            *((float4*)&w1s[row * 64 + cs * 4]) = wsrc[idx];
        }
    }
    __syncthreads();

    int ty = t >> 4;
    int tx = t & 15;

    float acc[8][8];
#pragma unroll
    for (int i = 0; i < 8; i++)
#pragma unroll
        for (int j = 0; j < 8; j++) acc[i][j] = 0.f;

#pragma unroll
    for (int c = 0; c < 16; c++) {
        int ca = (c + ty) & 15;
        int cb = (c + tx) & 15;
        float4 a[8], b[8];
#pragma unroll
        for (int i = 0; i < 8; i++)
            a[i] = *((const float4*)&htile[(ty * 8 + i) * 64 + ca * 4]);
#pragma unroll
        for (int j = 0; j < 8; j++)
            b[j] = *((const float4*)&w1s[(tx * 8 + j) * 64 + cb * 4]);
#pragma unroll
        for (int i = 0; i < 8; i++)
#pragma unroll
            for (int j = 0; j < 8; j++)
                acc[i][j] += a[i].x * b[j].x + a[i].y * b[j].y +
                             a[i].z * b[j].z + a[i].w * b[j].w;
    }

    float s1 = sinv[0];
    float4 b1lo = *((const float4*)&b1[tx * 8]);
    float4 b1hi = *((const float4*)&b1[tx * 8 + 4]);
    float bb[8] = {b1lo.x, b1lo.y, b1lo.z, b1lo.w, b1hi.x, b1hi.y, b1hi.z, b1hi.w};

#pragma unroll
    for (int i = 0; i < 8; i++) {
#pragma unroll
        for (int j = 0; j < 8; j++)
            acc[i][j] = fmaxf(fmaf(acc[i][j], s1, bb[j]), 0.f);
        float4 v0 = {acc[i][0], acc[i][1], acc[i][2], acc[i][3]};
        float4 v1 = {acc[i][4], acc[i][5], acc[i][6], acc[i][7]};
        float* dst = h1out + (size_t)(n0 + ty * 8 + i) * 128 + tx * 8;
        *((float4*)dst) = v0;
        *((float4*)(dst + 4)) = v1;
    }

    float* red = htile;
    float ps[8], qs[8];
#pragma unroll
    for (int j = 0; j < 8; j++) {
        float s = 0.f, q = 0.f;
#pragma unroll
        for (int i = 0; i < 8; i++) { s += acc[i][j]; q += acc[i][j] * acc[i][j]; }
        ps[j] = s; qs[j] = q;
    }
    __syncthreads();
#pragma unroll
    for (int j = 0; j < 8; j++) red[ty * 132 + tx * 8 + j] = ps[j];
    __syncthreads();
    if (t < 128) {
        float s = 0.f;
#pragma unroll
        for (int g = 0; g < 16; g++) s += red[g * 132 + t];
        partial[blockIdx.x * 256 + t] = s;
    }
    __syncthreads();
#pragma unroll
    for (int j = 0; j < 8; j++) red[ty * 132 + tx * 8 + j] = qs[j];
    __syncthreads();
    if (t < 128) {
        float s = 0.f;
#pragma unroll
        for (int g = 0; g < 16; g++) s += red[g * 132 + t];
        partial[blockIdx.x * 256 + 128 + t] = s;
    }
}

// ---------------- K4: fold BN + sigma2 into W2f, b2f (1 block) ----------------
__global__ __launch_bounds__(256) void k4_fold(const float* __restrict__ partial,
                                               int nblk, int N,
                                               const float* __restrict__ gamma,
                                               const float* __restrict__ beta,
                                               const float* __restrict__ W2,
                                               const float* __restrict__ b2,
                                               const float* __restrict__ sinv,
                                               float* __restrict__ W2f,
                                               float* __restrict__ b2f) {
    __shared__ float sums[256];
    __shared__ float a_s[128], c_s[128];
    int t = threadIdx.x;
    float t0 = 0.f, t1 = 0.f, t2 = 0.f, t3 = 0.f;
    for (int b = 0; b < nblk; b += 4) {
        t0 += partial[(b + 0) * 256 + t];
        t1 += partial[(b + 1) * 256 + t];
        t2 += partial[(b + 2) * 256 + t];
        t3 += partial[(b + 3) * 256 + t];
    }
    sums[t] = (t0 + t1) + (t2 + t3);
    __syncthreads();
    if (t < 128) {
        float mean = sums[t] / (float)N;
        float var = sums[t + 128] / (float)N - mean * mean;
        float rstd = rsqrtf(var + BN_EPS);
        float a = rstd * gamma[t];
        a_s[t] = a;
        c_s[t] = beta[t] - mean * a;
    }
    __syncthreads();
    if (t < 128) {
        float s2 = sinv[1];
        float accb = 0.f;
        for (int j = 0; j < 128; j++) {
            float w = W2[t * 128 + j] * s2;
            W2f[t * 128 + j] = w * a_s[j];
            accb += w * c_s[j];
        }
        b2f[t] = b2[t] + accb;
    }
}

// ---------------- K5: out = h1 @ W2f^T + b2f, in place on d_out ----------------
__global__ __launch_bounds__(256) void k5_gemm2(const float* __restrict__ W2f,
                                                const float* __restrict__ b2f,
                                                float* __restrict__ io) {
    __shared__ float htile[64 * 128];
    __shared__ float w2s[64 * 128];
    int t = threadIdx.x;
    int n0 = blockIdx.x * 64;
    int ty = t >> 4;
    int tx = t & 15;

    {
        const float4* src = (const float4*)(io + (size_t)n0 * 128);
#pragma unroll
        for (int i = 0; i < 8; i++) {
            int idx = i * 256 + t;
            int row = idx >> 5;
            int c = idx & 31;
            int cs = (c + (row >> 2)) & 31;
            *((float4*)&htile[row * 128 + cs * 4]) = src[idx];
        }
    }

    float acc[2][4][4];
#pragma unroll
    for (int hh = 0; hh < 2; hh++)
#pragma unroll
        for (int i = 0; i < 4; i++)
#pragma unroll
            for (int j = 0; j < 4; j++) acc[hh][i][j] = 0.f;

    for (int half = 0; half < 2; half++) {
        __syncthreads();
        const float4* wsrc = (const float4*)(W2f + (size_t)half * 64 * 128);
#pragma unroll
        for (int i = 0; i < 8; i++) {
            int idx = i * 256 + t;
            int row = idx >> 5;
            int c = idx & 31;
            int cs = (c + (row >> 2)) & 31;
            *((float4*)&w2s[row * 128 + cs * 4]) = wsrc[idx];
        }
        __syncthreads();

#pragma unroll
        for (int c = 0; c < 32; c++) {
            int ca = (c + ty) & 31;
            int cb = (c + tx) & 31;
            float4 a[4], b[4];
#pragma unroll
            for (int i = 0; i < 4; i++)
                a[i] = *((const float4*)&htile[(ty * 4 + i) * 128 + ca * 4]);
#pragma unroll
            for (int j = 0; j < 4; j++)
                b[j] = *((const float4*)&w2s[(tx * 4 + j) * 128 + cb * 4]);
#pragma unroll
            for (int i = 0; i < 4; i++)
#pragma unroll
                for (int j = 0; j < 4; j++)
                    acc[half][i][j] += a[i].x * b[j].x + a[i].y * b[j].y +
                                       a[i].z * b[j].z + a[i].w * b[j].w;
        }
    }

    float4 bf0 = *((const float4*)&b2f[tx * 4]);
    float4 bf1 = *((const float4*)&b2f[64 + tx * 4]);
#pragma unroll
    for (int i = 0; i < 4; i++) {
        float* dst = io + (size_t)(n0 + ty * 4 + i) * 128;
        float4 v0 = {acc[0][i][0] + bf0.x, acc[0][i][1] + bf0.y,
                     acc[0][i][2] + bf0.z, acc[0][i][3] + bf0.w};
        float4 v1 = {acc[1][i][0] + bf1.x, acc[1][i][1] + bf1.y,
                     acc[1][i][2] + bf1.z, acc[1][i][3] + bf1.w};
        *((float4*)(dst + tx * 4)) = v0;
        *((float4*)(dst + 64 + tx * 4)) = v1;
    }
}

extern "C" void kernel_launch(void* const* d_in, const int* in_sizes, int n_in,
                              void* d_out, int out_size, void* d_ws, size_t ws_size,
                              hipStream_t stream) {
    const float* x     = (const float*)d_in[0];
    const int*   ei    = (const int*)d_in[1];
    const float* W1    = (const float*)d_in[2];
    const float* b1    = (const float*)d_in[3];
    const float* u1    = (const float*)d_in[4];
    const float* gamma = (const float*)d_in[5];
    const float* beta  = (const float*)d_in[6];
    const float* W2    = (const float*)d_in[7];
    const float* b2    = (const float*)d_in[8];
    const float* u2    = (const float*)d_in[9];
    float* out = (float*)d_out;

    int N = in_sizes[0] / 64;     // 65536
    int E = in_sizes[1] / 2;      // 1048576
    int nblk1 = N / 128;          // 512 (k3 tiles)
    int nblk2 = N / 64;           // 1024 (k5 tiles)

    char* ws = (char*)d_ws;
    size_t off = 0;
    float* h       = (float*)(ws + off); off += (size_t)N * 64 * 4;      // 16 MB
    int*   deg     = (int*)(ws + off);   off += (size_t)N * 4;
    int*   offs    = (int*)(ws + off);   off += (size_t)(N + 1) * 4;
    int*   cursor  = (int*)(ws + off);   off += (size_t)(N + 16) * 4;
    int*   csr     = (int*)(ws + off);   off += (size_t)E * 4;           // 4 MB
    float* partial = (float*)(ws + off); off += (size_t)nblk1 * 256 * 4;
    float* sinv    = (float*)(ws + off); off += 16 * 4;
    float* W2f     = (float*)(ws + off); off += 128 * 128 * 4;
    float* b2f     = (float*)(ws + off);

    // CSR build
    kzero<<<(N + 255) / 256, 256, 0, stream>>>(deg, N);
    kcount<<<(E + 255) / 256, 256, 0, stream>>>(ei, deg, E);
    kscan<<<1, 1024, 0, stream>>>(deg, offs, cursor, N);
    kfill<<<(E + 255) / 256, 256, 0, stream>>>(ei, cursor, csr, E);
    // sigmas (small, independent)
    k2_sigma<<<1, 128, 0, stream>>>(W1, u1, W2, u2, sinv);
    // h = x + gather-sum
    kagg<<<(N * 64 + 255) / 256, 256, 0, stream>>>(offs, csr, x, h, N);
    // h1 = relu(gemm1) -> d_out, BN partials
    k3_gemm1<<<nblk1, 256, 0, stream>>>(h, W1, b1, sinv, out, partial);
    // fold BN + sigma2
    k4_fold<<<1, 256, 0, stream>>>(partial, nblk1, N, gamma, beta, W2, b2, sinv, W2f, b2f);
    // out = h1 @ W2f^T + b2f (in place)
    k5_gemm2<<<nblk2, 256, 0, stream>>>(W2f, b2f, out);
}

// Round 4
// 357.444 us; speedup vs baseline: 3.0417x; 1.4049x over previous
//
#include <hip/hip_runtime.h>

// N=65536, E=1048576, nfeat=64, nhid=128. Inputs fp32; edge_index int32.
// GEMMs run as bf16 MFMA (16x16x32), fp32 accumulate. BN folded into W2.

#define BN_EPS 1e-5f

typedef float f4 __attribute__((ext_vector_type(4)));
typedef short bf8 __attribute__((ext_vector_type(8)));   // 8 bf16 = 4 VGPRs

__device__ inline short f2bf(float f) {
    unsigned u = __float_as_uint(f);
    u = u + 0x7fffu + ((u >> 16) & 1u);   // round-to-nearest-even
    return (short)(u >> 16);
}

// ---------------- CSR build: zero / count / scan / fill ----------------
__global__ __launch_bounds__(256) void kzero(int* __restrict__ deg, int N) {
    int i = blockIdx.x * 256 + threadIdx.x;
    if (i < N) deg[i] = 0;
}

__global__ __launch_bounds__(256) void kcount(const int* __restrict__ ei,
                                              int* __restrict__ deg, int E) {
    int e = blockIdx.x * 256 + threadIdx.x;
    if (e < E) atomicAdd(&deg[ei[E + e]], 1);
}

// single block, 1024 threads, chunk = 64 -> N = 65536
__global__ __launch_bounds__(1024) void kscan(const int* __restrict__ deg,
                                              int* __restrict__ offset,
                                              int* __restrict__ cursor, int N) {
    __shared__ int part[1024];
    int t = threadIdx.x;
    int base = t * 64;
    int sum = 0;
#pragma unroll 8
    for (int i = 0; i < 64; i++) sum += deg[base + i];
    part[t] = sum;
    __syncthreads();
    for (int off = 1; off < 1024; off <<= 1) {
        int v = (t >= off) ? part[t - off] : 0;
        __syncthreads();
        part[t] += v;
        __syncthreads();
    }
    int run = part[t] - sum;
#pragma unroll 8
    for (int i = 0; i < 64; i++) {
        int d = deg[base + i];
        offset[base + i] = run;
        cursor[base + i] = run;
        run += d;
    }
    if (t == 1023) offset[N] = run;
}

__global__ __launch_bounds__(256) void kfill(const int* __restrict__ ei,
                                             int* __restrict__ cursor,
                                             int* __restrict__ csr, int E) {
    int e = blockIdx.x * 256 + threadIdx.x;
    if (e < E) {
        int src = ei[e];
        int dst = ei[E + e];
        int pos = atomicAdd(&cursor[dst], 1);
        csr[pos] = src;
    }
}

// ---------------- kagg: hbf[n] = bf16(x[n] + sum_{src} x[src]) ----------------
__global__ __launch_bounds__(256) void kagg(const int* __restrict__ offset,
                                            const int* __restrict__ csr,
                                            const float* __restrict__ x,
                                            short* __restrict__ hbf, int N) {
    int w = (blockIdx.x * 256 + threadIdx.x) >> 6;
    int lane = threadIdx.x & 63;
    if (w >= N) return;
    int beg = offset[w];
    int end = offset[w + 1];
    float a0 = x[(size_t)w * 64 + lane];
    float a1 = 0.f, a2 = 0.f, a3 = 0.f;
    int j = beg;
    for (; j + 4 <= end; j += 4) {
        int s0 = csr[j + 0];
        int s1 = csr[j + 1];
        int s2 = csr[j + 2];
        int s3 = csr[j + 3];
        a0 += x[(size_t)s0 * 64 + lane];
        a1 += x[(size_t)s1 * 64 + lane];
        a2 += x[(size_t)s2 * 64 + lane];
        a3 += x[(size_t)s3 * 64 + lane];
    }
    for (; j < end; j++) a0 += x[(size_t)csr[j] * 64 + lane];
    hbf[(size_t)w * 64 + lane] = f2bf((a0 + a1) + (a2 + a3));
}

// ---------------- kcvt: fp32 -> bf16 (for W1) ----------------
__global__ __launch_bounds__(256) void kcvt(const float* __restrict__ w,
                                            short* __restrict__ o, int n) {
    int i = blockIdx.x * 256 + threadIdx.x;
    if (i < n) o[i] = f2bf(w[i]);
}

// ---------------- K2: spectral-norm sigmas (1 block, 128 thr, fp32) ----------------
__global__ __launch_bounds__(128) void k2_sigma(const float* __restrict__ W1,
                                                const float* __restrict__ u1,
                                                const float* __restrict__ W2,
                                                const float* __restrict__ u2,
                                                float* __restrict__ sinv) {
    __shared__ float v[128];
    __shared__ float red[128];
    int t = threadIdx.x;

    float vj = 0.f;
    if (t < 64) {
        for (int i = 0; i < 128; i++) vj += W1[i * 64 + t] * u1[i];
    }
    red[t] = (t < 64) ? vj * vj : 0.f;
    __syncthreads();
    for (int s = 64; s > 0; s >>= 1) { if (t < s) red[t] += red[t + s]; __syncthreads(); }
    float nv = sqrtf(red[0]);
    __syncthreads();
    if (t < 64) v[t] = vj / (nv + 1e-12f);
    __syncthreads();
    float ti = 0.f;
    for (int j = 0; j < 64; j++) ti += W1[t * 64 + j] * v[j];
    red[t] = ti * ti;
    __syncthreads();
    for (int s = 64; s > 0; s >>= 1) { if (t < s) red[t] += red[t + s]; __syncthreads(); }
    if (t == 0) {
        float nt2 = red[0];
        float nt = sqrtf(nt2);
        sinv[0] = (nt + 1e-12f) / nt2;
    }
    __syncthreads();

    float v2 = 0.f;
    for (int i = 0; i < 128; i++) v2 += W2[i * 128 + t] * u2[i];
    red[t] = v2 * v2;
    __syncthreads();
    for (int s = 64; s > 0; s >>= 1) { if (t < s) red[t] += red[t + s]; __syncthreads(); }
    nv = sqrtf(red[0]);
    __syncthreads();
    v[t] = v2 / (nv + 1e-12f);
    __syncthreads();
    ti = 0.f;
    for (int j = 0; j < 128; j++) ti += W2[t * 128 + j] * v[j];
    red[t] = ti * ti;
    __syncthreads();
    for (int s = 64; s > 0; s >>= 1) { if (t < s) red[t] += red[t + s]; __syncthreads(); }
    if (t == 0) {
        float nt2 = red[0];
        float nt = sqrtf(nt2);
        sinv[1] = (nt + 1e-12f) / nt2;
    }
}

// ---------------- K3: h1 = relu(s1*(h @ W1^T) + b1) via MFMA + BN partials ----
// 128 nodes x 128 outs per block (256 thr = 4 waves), K=64 (2 mfma K-steps).
// LDS union: [hs 128x64 bf16 | w1s 128x64 bf16] = 32 KB, reused as bf16
// out-tile 128x128 for the coalesced writeout. XOR-chunk swizzle everywhere.
__global__ __launch_bounds__(256) void k3_gemm1(const short* __restrict__ hbf,
                                                const short* __restrict__ w1bf,
                                                const float* __restrict__ b1,
                                                const float* __restrict__ sinv,
                                                short* __restrict__ h1bf,
                                                float* __restrict__ partial) {
    __shared__ short u[16384];          // 32 KB
    __shared__ float red1[512], red2[512];
    int t = threadIdx.x;
    int n0 = blockIdx.x * 128;

    // stage h tile + W1 (row-major bf16, 8 chunks of 16B per row, chunk^row&7)
    const bf8* hsrc = (const bf8*)(hbf + (size_t)n0 * 64);
    const bf8* wsrc = (const bf8*)w1bf;
#pragma unroll
    for (int i = 0; i < 4; i++) {
        int idx = i * 256 + t;          // 0..1023
        int row = idx >> 3, c = idx & 7;
        int cs = c ^ (row & 7);
        *(bf8*)&u[row * 64 + cs * 8] = hsrc[idx];
    }
#pragma unroll
    for (int i = 0; i < 4; i++) {
        int idx = i * 256 + t;
        int row = idx >> 3, c = idx & 7;
        int cs = c ^ (row & 7);
        *(bf8*)&u[8192 + row * 64 + cs * 8] = wsrc[idx];
    }
    __syncthreads();

    int w = t >> 6;
    int l15 = t & 15, quad = (t & 63) >> 4;

    f4 acc[2][8];
#pragma unroll
    for (int mt = 0; mt < 2; mt++)
#pragma unroll
        for (int nt = 0; nt < 8; nt++) acc[mt][nt] = (f4){0.f, 0.f, 0.f, 0.f};

#pragma unroll
    for (int ks = 0; ks < 2; ks++) {
        bf8 a[2], b[8];
#pragma unroll
        for (int mt = 0; mt < 2; mt++) {
            int node = w * 32 + mt * 16 + l15;       // A[m=lane&15][k=quad*8+j]
            int cs = (ks * 4 + quad) ^ (node & 7);
            a[mt] = *(const bf8*)&u[node * 64 + cs * 8];
        }
#pragma unroll
        for (int nt = 0; nt < 8; nt++) {
            int o = nt * 16 + l15;                   // B from W1 row (B^T layout)
            int cs = (ks * 4 + quad) ^ (o & 7);
            b[nt] = *(const bf8*)&u[8192 + o * 64 + cs * 8];
        }
#pragma unroll
        for (int mt = 0; mt < 2; mt++)
#pragma unroll
            for (int nt = 0; nt < 8; nt++)
                acc[mt][nt] = __builtin_amdgcn_mfma_f32_16x16x32_bf16(
                    a[mt], b[nt], acc[mt][nt], 0, 0, 0);
    }

    // epilogue: relu(acc*s1 + b1) + BN column sums
    float s1 = sinv[0];
    float b1v[8];
#pragma unroll
    for (int nt = 0; nt < 8; nt++) b1v[nt] = b1[nt * 16 + l15];

#pragma unroll
    for (int nt = 0; nt < 8; nt++) {
        float s = 0.f, q = 0.f;
#pragma unroll
        for (int mt = 0; mt < 2; mt++)
#pragma unroll
            for (int r = 0; r < 4; r++) {
                float v = fmaxf(fmaf(acc[mt][nt][r], s1, b1v[nt]), 0.f);
                acc[mt][nt][r] = v;
                s += v; q += v * v;
            }
        s += __shfl_xor(s, 16); s += __shfl_xor(s, 32);
        q += __shfl_xor(q, 16); q += __shfl_xor(q, 32);
        if (quad == 0) {
            red1[w * 128 + nt * 16 + l15] = s;
            red2[w * 128 + nt * 16 + l15] = q;
        }
    }
    __syncthreads();   // all fragment reads done -> safe to reuse u as out-tile

    // write bf16 out-tile into u (128x128, 16 chunks/row, chunk^row&15)
#pragma unroll
    for (int mt = 0; mt < 2; mt++)
#pragma unroll
        for (int nt = 0; nt < 8; nt++) {
            int col = nt * 16 + l15;
#pragma unroll
            for (int r = 0; r < 4; r++) {
                int node = w * 32 + mt * 16 + quad * 4 + r;   // C/D: row=quad*4+reg
                int cs = (col >> 3) ^ (node & 15);
                u[node * 128 + cs * 8 + (col & 7)] = f2bf(acc[mt][nt][r]);
            }
        }
    __syncthreads();

    // coalesced readout to global h1bf + BN partial writes
    short* dst = h1bf + (size_t)n0 * 128;
#pragma unroll
    for (int i = 0; i < 8; i++) {
        int idx = i * 256 + t;          // 0..2047
        int row = idx >> 4, c = idx & 15;
        int cs = c ^ (row & 15);
        *(bf8*)&dst[idx * 8] = *(const bf8*)&u[row * 128 + cs * 8];
    }
    if (t < 128) {
        float s = red1[t] + red1[128 + t] + red1[256 + t] + red1[384 + t];
        float q = red2[t] + red2[128 + t] + red2[256 + t] + red2[384 + t];
        partial[blockIdx.x * 256 + t] = s;
        partial[blockIdx.x * 256 + 128 + t] = q;
    }
}

// ---------------- K4: fold BN + sigma2 into W2f(bf16), b2f(fp32) ----------------
__global__ __launch_bounds__(256) void k4_fold(const float* __restrict__ partial,
                                               int nblk, int N,
                                               const float* __restrict__ gamma,
                                               const float* __restrict__ beta,
                                               const float* __restrict__ W2,
                                               const float* __restrict__ b2,
                                               const float* __restrict__ sinv,
                                               short* __restrict__ W2fbf,
                                               float* __restrict__ b2f) {
    __shared__ float sums[256];
    __shared__ float a_s[128], c_s[128];
    int t = threadIdx.x;
    float t0 = 0.f, t1 = 0.f, t2 = 0.f, t3 = 0.f;
    for (int b = 0; b < nblk; b += 4) {
        t0 += partial[(b + 0) * 256 + t];
        t1 += partial[(b + 1) * 256 + t];
        t2 += partial[(b + 2) * 256 + t];
        t3 += partial[(b + 3) * 256 + t];
    }
    sums[t] = (t0 + t1) + (t2 + t3);
    __syncthreads();
    if (t < 128) {
        float mean = sums[t] / (float)N;
        float var = sums[t + 128] / (float)N - mean * mean;
        float rstd = rsqrtf(var + BN_EPS);
        float a = rstd * gamma[t];
        a_s[t] = a;
        c_s[t] = beta[t] - mean * a;
    }
    __syncthreads();
    if (t < 128) {
        float s2 = sinv[1];
        float accb = 0.f;
        for (int j = 0; j < 128; j++) {
            float w = W2[t * 128 + j] * s2;
            W2fbf[t * 128 + j] = f2bf(w * a_s[j]);
            accb += w * c_s[j];
        }
        b2f[t] = b2[t] + accb;
    }
}

// ---------------- K5: out = h1 @ W2f^T + b2f via MFMA ----------------
// 128 nodes x 128 outs per block, K=128 (4 mfma K-steps). LDS 64 KB.
__global__ __launch_bounds__(256) void k5_gemm2(const short* __restrict__ h1bf,
                                                const short* __restrict__ w2fbf,
                                                const float* __restrict__ b2f,
                                                float* __restrict__ out) {
    __shared__ short s5[32768];     // [h1s 128x128 | w2s 128x128] bf16
    int t = threadIdx.x;
    int n0 = blockIdx.x * 128;

    const bf8* hsrc = (const bf8*)(h1bf + (size_t)n0 * 128);
    const bf8* wsrc = (const bf8*)w2fbf;
#pragma unroll
    for (int i = 0; i < 8; i++) {
        int idx = i * 256 + t;          // 0..2047
        int row = idx >> 4, c = idx & 15;
        int cs = c ^ (row & 15);
        *(bf8*)&s5[row * 128 + cs * 8] = hsrc[idx];
    }
#pragma unroll
    for (int i = 0; i < 8; i++) {
        int idx = i * 256 + t;
        int row = idx >> 4, c = idx & 15;
        int cs = c ^ (row & 15);
        *(bf8*)&s5[16384 + row * 128 + cs * 8] = wsrc[idx];
    }
    __syncthreads();

    int w = t >> 6;
    int l15 = t & 15, quad = (t & 63) >> 4;

    f4 acc[2][8];
#pragma unroll
    for (int mt = 0; mt < 2; mt++)
#pragma unroll
        for (int nt = 0; nt < 8; nt++) acc[mt][nt] = (f4){0.f, 0.f, 0.f, 0.f};

#pragma unroll
    for (int ks = 0; ks < 4; ks++) {
        bf8 a[2], b[8];
#pragma unroll
        for (int mt = 0; mt < 2; mt++) {
            int node = w * 32 + mt * 16 + l15;
            int cs = (ks * 4 + quad) ^ (node & 15);
            a[mt] = *(const bf8*)&s5[node * 128 + cs * 8];
        }
#pragma unroll
        for (int nt = 0; nt < 8; nt++) {
            int o = nt * 16 + l15;
            int cs = (ks * 4 + quad) ^ (o & 15);
            b[nt] = *(const bf8*)&s5[16384 + o * 128 + cs * 8];
        }
#pragma unroll
        for (int mt = 0; mt < 2; mt++)
#pragma unroll
            for (int nt = 0; nt < 8; nt++)
                acc[mt][nt] = __builtin_amdgcn_mfma_f32_16x16x32_bf16(
                    a[mt], b[nt], acc[mt][nt], 0, 0, 0);
    }

    float b2v[8];
#pragma unroll
    for (int nt = 0; nt < 8; nt++) b2v[nt] = b2f[nt * 16 + l15];

#pragma unroll
    for (int mt = 0; mt < 2; mt++)
#pragma unroll
        for (int nt = 0; nt < 8; nt++)
#pragma unroll
            for (int r = 0; r < 4; r++) {
                int node = n0 + w * 32 + mt * 16 + quad * 4 + r;
                out[(size_t)node * 128 + nt * 16 + l15] = acc[mt][nt][r] + b2v[nt];
            }
}

extern "C" void kernel_launch(void* const* d_in, const int* in_sizes, int n_in,
                              void* d_out, int out_size, void* d_ws, size_t ws_size,
                              hipStream_t stream) {
    const float* x     = (const float*)d_in[0];
    const int*   ei    = (const int*)d_in[1];
    const float* W1    = (const float*)d_in[2];
    const float* b1    = (const float*)d_in[3];
    const float* u1    = (const float*)d_in[4];
    const float* gamma = (const float*)d_in[5];
    const float* beta  = (const float*)d_in[6];
    const float* W2    = (const float*)d_in[7];
    const float* b2    = (const float*)d_in[8];
    const float* u2    = (const float*)d_in[9];
    float* out = (float*)d_out;

    int N = in_sizes[0] / 64;     // 65536
    int E = in_sizes[1] / 2;      // 1048576
    int nblk = N / 128;           // 512

    char* ws = (char*)d_ws;
    size_t off = 0;
    short* hbf     = (short*)(ws + off); off += (size_t)N * 64 * 2;      // 8 MB
    short* h1bf    = (short*)(ws + off); off += (size_t)N * 128 * 2;     // 16 MB
    int*   csr     = (int*)(ws + off);   off += (size_t)E * 4;           // 4 MB
    int*   deg     = (int*)(ws + off);   off += (size_t)N * 4;
    int*   offs    = (int*)(ws + off);   off += (size_t)(N + 16) * 4;
    int*   cursor  = (int*)(ws + off);   off += (size_t)(N + 16) * 4;
    float* partial = (float*)(ws + off); off += (size_t)nblk * 256 * 4;  // 512 KB
    float* sinv    = (float*)(ws + off); off += 16 * 4;
    float* b2f     = (float*)(ws + off); off += 128 * 4;
    short* w1bf    = (short*)(ws + off); off += 128 * 64 * 2;
    short* w2fbf   = (short*)(ws + off); off += 128 * 128 * 2;

    // CSR build
    kzero<<<(N + 255) / 256, 256, 0, stream>>>(deg, N);
    kcount<<<(E + 255) / 256, 256, 0, stream>>>(ei, deg, E);
    kscan<<<1, 1024, 0, stream>>>(deg, offs, cursor, N);
    kfill<<<(E + 255) / 256, 256, 0, stream>>>(ei, cursor, csr, E);
    // sigmas + W1 cast (small, independent)
    k2_sigma<<<1, 128, 0, stream>>>(W1, u1, W2, u2, sinv);
    kcvt<<<32, 256, 0, stream>>>(W1, w1bf, 128 * 64);
    // h = x + gather-sum  (bf16 out)
    kagg<<<(N * 64 + 255) / 256, 256, 0, stream>>>(offs, csr, x, hbf, N);
    // h1 = relu(gemm1) -> bf16 + BN partials
    k3_gemm1<<<nblk, 256, 0, stream>>>(hbf, w1bf, b1, sinv, h1bf, partial);
    // fold BN + sigma2 into bf16 W2f
    k4_fold<<<1, 256, 0, stream>>>(partial, nblk, N, gamma, beta, W2, b2, sinv, w2fbf, b2f);
    // out = h1 @ W2f^T + b2f
    k5_gemm2<<<nblk, 256, 0, stream>>>(h1bf, w2fbf, b2f, out);
}